// Round 12
// baseline (400.346 us; speedup 1.0000x reference)
//
#include <hip/hip_runtime.h>
#include <stdint.h>

typedef __bf16 bf16x8 __attribute__((ext_vector_type(8)));
typedef float  f32x4  __attribute__((ext_vector_type(4)));
typedef int    i32x4  __attribute__((ext_vector_type(4)));
typedef int    i32x8  __attribute__((ext_vector_type(8)));
typedef float  f32x16 __attribute__((ext_vector_type(16)));

// tanh(x) = 1 - 2/(exp(2x)+1) with fast v_rcp. |err| ~1e-7, exact at +/-inf.
__device__ __forceinline__ float tanh_fast(float x){
    float e = __expf(2.0f * x);
    return 1.0f - 2.0f * __builtin_amdgcn_rcpf(e + 1.0f);
}
// 4*tanh(x) (so fp4 e2m1 of result + MFMA scale 2^-2 reconstructs tanh)
__device__ __forceinline__ float tanh4_fast(float x){
    float e = __expf(2.0f * x);
    return fmaf(-8.0f, __builtin_amdgcn_rcpf(e + 1.0f), 4.0f);
}

__device__ __forceinline__ unsigned short f2bf(float f){
    unsigned int u = __float_as_uint(f);
    u = (u + 0x7fffu + ((u >> 16) & 1u)) >> 16;   // RNE
    return (unsigned short)u;
}

// pack 2 floats (range (-4,4)) as 2 e2m1 nibbles into byte SEL of `old`.
template<int SEL>
__device__ __forceinline__ unsigned int pk4(unsigned int old, float a, float b){
#if defined(__has_builtin) && __has_builtin(__builtin_amdgcn_cvt_scalef32_pk_fp4_f32)
    return __builtin_amdgcn_cvt_scalef32_pk_fp4_f32(old, a, b, 1.0f, SEL);
#else
    float fa = fabsf(a), fb = fabsf(b);
    unsigned int ma = fa < 0.25f ? 0u : fa < 0.75f ? 1u : fa < 1.25f ? 2u :
                      fa < 1.75f ? 3u : fa < 2.5f  ? 4u : fa < 3.5f  ? 5u :
                      fa < 5.0f  ? 6u : 7u;
    unsigned int mb = fb < 0.25f ? 0u : fb < 0.75f ? 1u : fb < 1.25f ? 2u :
                      fb < 1.75f ? 3u : fb < 2.5f  ? 4u : fb < 3.5f  ? 5u :
                      fb < 5.0f  ? 6u : 7u;
    ma |= (a < 0.0f ? 8u : 0u); mb |= (b < 0.0f ? 8u : 0u);
    return old | ((ma | (mb << 4)) << (8 * SEL));
#endif
}

// unpack 2 bf16 (one uint) -> 2 floats
#define B2F(u, lo, hi) { lo = __uint_as_float((u) << 16); hi = __uint_as_float((u) & 0xffff0000u); }

// ===== stage 1: w1t transpose | pairs | w2b(fp4) | value-head | zero-out | qctr =====
__global__ __launch_bounds__(256) void k_stage1(
    const float* __restrict__ ef,  const float* __restrict__ aW1,
    const float* __restrict__ aW2,
    const float* __restrict__ cW1, const float* __restrict__ cb1,
    const float* __restrict__ cW2, const float* __restrict__ cb2,
    const float* __restrict__ cW3, const float* __restrict__ cb3,
    int* __restrict__ pairs, unsigned short* __restrict__ w1t,
    unsigned char* __restrict__ w2b, float* __restrict__ out, int* __restrict__ qctr)
{
    int blk = blockIdx.x;
    int t = threadIdx.x;
    __shared__ int s_base, s_woff[4], s_wc[4];
    __shared__ float gs[256], h1[512], h2[512], wred[4];

    if (blk == 256 && t == 0) qctr[0] = 0;

    if (blk < 256){
        // ---- aW1[256:768] -> bf16, transposed [s][col][k] ----
        int tid = blk * 256 + t;                        // 65536 threads
        int k8 = tid & 31, c = (tid >> 5) & 1023, s = tid >> 15;
        const float* src = aW1 + (size_t)(256 + s * 256 + k8 * 8) * 1024 + c;
        unsigned int* dst = (unsigned int*)(w1t + (size_t)tid * 8);
#pragma unroll
        for (int jj = 0; jj < 4; ++jj){
            unsigned short lo = f2bf(src[(size_t)(2 * jj) * 1024]);
            unsigned short hi = f2bf(src[(size_t)(2 * jj + 1) * 1024]);
            dst[jj] = (unsigned int)lo | ((unsigned int)hi << 16);
        }
    } else if (blk < 288){
        // ---- deterministic compaction of active mask positions ----
        int b = blk - 256;
        if (t == 0) s_base = 0;
        __syncthreads();
        int lane = t & 63, w = t >> 6;
        for (int ch = 0; ch < 40; ++ch){
            int pos = ch * 256 + t;
            bool valid = false;
            if (pos < 10000){
                int r = pos / 100, c = pos - (pos / 100) * 100;
                valid = ef[(size_t)b * 35956 + (size_t)(1 + r) * 356 + 256 + c] != 0.0f;
            }
            unsigned long long bal = __ballot(valid);
            if (lane == 0) s_wc[w] = __popcll(bal);
            __syncthreads();
            if (t == 0){
                int r = s_base;
                for (int q = 0; q < 4; ++q){ s_woff[q] = r; r += s_wc[q]; }
                s_base = r;
            }
            __syncthreads();
            if (valid){
                int rank = __popcll(bal & ((1ull << lane) - 1ull));
                int o = s_woff[w] + rank;
                if (o < 5000) pairs[b * 5000 + o] = pos;
            }
            __syncthreads();
        }
    } else if (blk < 416){
        // ---- aW2 -> fp4 e2m1 x 2^-7 (uniform MX scale 0x78), B-operand blocked ----
        int tid = (blk - 288) * 256 + t;                // 32768 threads
        int lane = tid & 63, kt = (tid >> 6) & 15, ct = tid >> 10;
        int lh = lane >> 5, n = lane & 31;
        const float* src = aW2 + (size_t)(kt * 64 + lh * 32) * 1024 + ct * 32 + n;
        unsigned int d[4] = {0u, 0u, 0u, 0u};
#pragma unroll
        for (int j = 0; j < 32; ++j){
            float a = src[(size_t)j * 1024] * 128.0f;   // undo 2^-7 scale
            float f = fabsf(a);
            unsigned int m = f < 0.25f ? 0u : f < 0.75f ? 1u : f < 1.25f ? 2u :
                             f < 1.75f ? 3u : f < 2.5f  ? 4u : f < 3.5f  ? 5u :
                             f < 5.0f  ? 6u : 7u;
            unsigned int nib = m | (a < 0.0f ? 8u : 0u);
            d[j >> 3] |= nib << (4 * (j & 7));
        }
        *(uint4*)(w2b + (size_t)(ct * 16 + kt) * 1024 + lane * 16) =
            make_uint4(d[0], d[1], d[2], d[3]);
    } else if (blk < 448){
        // ---- value head (tiny, fp32) ----
        int b = blk - 416;
        gs[t] = ef[(size_t)b * 35956 + t];
        __syncthreads();
        for (int o = t; o < 512; o += 256){
            float a = cb1[o];
            for (int i = 0; i < 256; ++i) a += gs[i] * cW1[(size_t)i * 512 + o];
            h1[o] = tanh_fast(a);
        }
        __syncthreads();
        for (int o = t; o < 512; o += 256){
            float a = cb2[o];
            for (int i = 0; i < 512; ++i) a += h1[i] * cW2[(size_t)i * 512 + o];
            h2[o] = tanh_fast(a);
        }
        __syncthreads();
        float p = h2[t] * cW3[t] + h2[t + 256] * cW3[t + 256];
        for (int m = 32; m >= 1; m >>= 1) p += __shfl_xor(p, m);
        if ((t & 63) == 0) wred[t >> 6] = p;
        __syncthreads();
        if (t == 0) out[320000 + b] = wred[0] + wred[1] + wred[2] + wred[3] + cb3[0];
    } else {
        // ---- zero the scatter region out[0:320000) ----
        int i = (blk - 448) * 256 + t;
        if (i < 80000) ((float4*)out)[i] = make_float4(0.f, 0.f, 0.f, 0.f);
    }
}

// ---- P{1,2}[b][node][c] = nodes_b @ bf16(aW1 slice) (+g1+ab1 for s=0), bf16 out ----
__global__ __launch_bounds__(256) void k_p(const float* __restrict__ ef,
        const unsigned short* __restrict__ w1t, unsigned short* __restrict__ P,
        const float* __restrict__ aW1, const float* __restrict__ ab1){
    __shared__ __align__(16) unsigned short an[112 * 264];
    __shared__ float gsh[256], gpart[4][64];
    int blk = blockIdx.x;
    int cb = blk & 15, s = (blk >> 4) & 1, b = blk >> 5;
    int t = threadIdx.x;
    for (int e = t; e < 25600; e += 256){            // stage nodes as bf16
        int row = e >> 8, col = e & 255;
        an[row * 264 + col] = f2bf(ef[(size_t)b * 35956 + (size_t)(1 + row) * 356 + col]);
    }
    for (int e = t; e < 3168; e += 256) an[26400 + e] = 0;  // zero pad rows 100..111
    gsh[t] = ef[(size_t)b * 35956 + t];
    __syncthreads();
    if (s == 0){                                     // inline g1 partial: 4 quarters x 64 cols
        int cl = t & 63, q = t >> 6;
        const float* a1p = aW1 + (size_t)(q * 64) * 1024 + cb * 64 + cl;
        float p = 0.f;
        for (int i = 0; i < 64; ++i) p += gsh[q * 64 + i] * a1p[(size_t)i * 1024];
        gpart[q][cl] = p;
    }
    __syncthreads();
    int w = t >> 6, lane = t & 63, quad = lane >> 4, n = lane & 15;
    int c = cb * 64 + w * 16 + n;
    f32x4 acc[7];
#pragma unroll
    for (int m = 0; m < 7; ++m){ f32x4 z = {0.f, 0.f, 0.f, 0.f}; acc[m] = z; }
    const bf16x8* wp = (const bf16x8*)(w1t + (size_t)(s * 1024 + c) * 256);
#pragma unroll
    for (int kt = 0; kt < 8; ++kt){
        bf16x8 bfr = wp[kt * 4 + quad];
#pragma unroll
        for (int m = 0; m < 7; ++m){
            const bf16x8* ap = (const bf16x8*)(an + (m * 16 + n) * 264 + kt * 32 + quad * 8);
            acc[m] = __builtin_amdgcn_mfma_f32_16x16x32_bf16(*ap, bfr, acc[m], 0, 0, 0);
        }
    }
    int cw = w * 16 + n;
    float addv = (s == 0)
        ? (gpart[0][cw] + gpart[1][cw] + gpart[2][cw] + gpart[3][cw] + ab1[c]) : 0.0f;
    size_t base = (size_t)s * 3276800 + (size_t)b * 102400;
#pragma unroll
    for (int m = 0; m < 7; ++m){
        int r0 = m * 16 + quad * 4;
#pragma unroll
        for (int r = 0; r < 4; ++r){
            int row = r0 + r;
            if (row < 100) P[base + (size_t)row * 1024 + c] = f2bf(acc[m][r] + addv);
        }
    }
}

// phase-1 helper: build one 32-row tile's fp4 A fragments (e2m1 of 4*tanh)
__device__ __forceinline__ void build_af4(const uint4* __restrict__ pa,
                                          const uint4* __restrict__ pb, i32x4* af){
#pragma unroll
    for (int kt = 0; kt < 16; ++kt){
        uint4 qa[4], qb[4];
#pragma unroll
        for (int j = 0; j < 4; ++j){ qa[j] = pa[kt * 8 + j]; qb[j] = pb[kt * 8 + j]; }
        unsigned int d[4];
#pragma unroll
        for (int j = 0; j < 4; ++j){
            float a0, a1, b0, b1;
            unsigned int dd = 0;
            B2F(qa[j].x, a0, a1); B2F(qb[j].x, b0, b1);
            dd = pk4<0>(dd, tanh4_fast(a0 + b0), tanh4_fast(a1 + b1));
            B2F(qa[j].y, a0, a1); B2F(qb[j].y, b0, b1);
            dd = pk4<1>(dd, tanh4_fast(a0 + b0), tanh4_fast(a1 + b1));
            B2F(qa[j].z, a0, a1); B2F(qb[j].z, b0, b1);
            dd = pk4<2>(dd, tanh4_fast(a0 + b0), tanh4_fast(a1 + b1));
            B2F(qa[j].w, a0, a1); B2F(qb[j].w, b0, b1);
            dd = pk4<3>(dd, tanh4_fast(a0 + b0), tanh4_fast(a1 + b1));
            d[j] = dd;
        }
        i32x4 f = {(int)d[0], (int)d[1], (int)d[2], (int)d[3]};
        af[kt] = f;
    }
}

// lower-half = a, upper-half undef (cbsz=4 -> HW reads only v[0:3])
__device__ __forceinline__ i32x8 lo4(i32x4 a){
    return __builtin_shufflevector(a, a, 0, 1, 2, 3, -1, -1, -1, -1);
}

// ---------------- fused layer1-gather + fp4xfp4 layer2 GEMM + layer3 dot ----------------
// Wave-autonomous, NO LDS, NO barriers: B (512 KB fp4) is L2-resident and read
// directly per-fragment (wave-coalesced 1KB loads). 64 rows/wave (two 32-row MFMA
// tiles share every B fragment). Wave-level queue of 2528 64-row units.
__global__ __launch_bounds__(256, 2) void k_main(
    const int* __restrict__ pairs,
    const unsigned short* __restrict__ P1, const unsigned short* __restrict__ P2,
    const unsigned char* __restrict__ w2b, const float* __restrict__ ab2,
    const float* __restrict__ aW3, float* __restrict__ logits, int* __restrict__ qctr)
{
    int t = threadIdx.x, lane = t & 63;
    int lrow = lane & 31, lh = lane >> 5;
    const unsigned char* wb = w2b + lane * 16;

    for (;;){
        int u = 0;
        if (lane == 0) u = atomicAdd(qctr, 1);
        u = __shfl(u, 0);
        if (u >= 2528) break;                 // 32 batches x 79 units of 64 rows
        int b = u / 79, r0 = (u - b * 79) * 64;

        int g0 = r0 + lrow, g1 = r0 + 32 + lrow;
        int pidx0 = pairs[b * 5000 + (g0 < 5000 ? g0 : 4999)];
        int pidx1 = pairs[b * 5000 + (g1 < 5000 ? g1 : 4999)];
        int i10 = pidx0 / 100, i20 = pidx0 - i10 * 100;
        int i11 = pidx1 / 100, i21 = pidx1 - i11 * 100;

        i32x4 afa[16], afb[16];
        build_af4((const uint4*)(P1 + (((size_t)(b * 100 + i10)) << 10)) + lh * 4,
                  (const uint4*)(P2 + (((size_t)(b * 100 + i20)) << 10)) + lh * 4, afa);
        build_af4((const uint4*)(P1 + (((size_t)(b * 100 + i11)) << 10)) + lh * 4,
                  (const uint4*)(P2 + (((size_t)(b * 100 + i21)) << 10)) + lh * 4, afb);

        float prt0[16], prt1[16];
#pragma unroll
        for (int r = 0; r < 16; ++r){ prt0[r] = 0.f; prt1[r] = 0.f; }
        f32x16 acc0, acc1;

        for (int ct = 0; ct < 32; ++ct){
#pragma unroll
            for (int r = 0; r < 16; ++r){ acc0[r] = 0.f; acc1[r] = 0.f; }
            const unsigned char* bs = wb + (size_t)ct * 16384;
#pragma unroll
            for (int kt = 0; kt < 16; ++kt){
                uint4 q = *(const uint4*)(bs + kt * 1024);
                i32x8 bop = {(int)q.x, (int)q.y, (int)q.z, (int)q.w, 0, 0, 0, 0};
                // cbsz=4: A fp4 (scale 2^-2 = 0x7D); blgp=4: B fp4 (scale 2^-7 = 0x78)
                acc0 = __builtin_amdgcn_mfma_scale_f32_32x32x64_f8f6f4(
                           lo4(afa[kt]), bop, acc0, 4, 4, 0, 0x7D7D7D7D, 0, 0x78787878);
                acc1 = __builtin_amdgcn_mfma_scale_f32_32x32x64_f8f6f4(
                           lo4(afb[kt]), bop, acc1, 4, 4, 0, 0x7D7D7D7D, 0, 0x78787878);
            }
            int c = ct * 32 + lrow;
            float w3 = aW3[c], bias = ab2[c];
#pragma unroll
            for (int r = 0; r < 16; ++r){
                prt0[r] += tanh_fast(acc0[r] + bias) * w3;
                prt1[r] += tanh_fast(acc1[r] + bias) * w3;
            }
        }

        // reduce each reg's partial over the 32 cols (lanes within each half-wave)
#pragma unroll
        for (int r = 0; r < 16; ++r){
            float v0 = prt0[r], v1 = prt1[r];
            v0 += __shfl_xor(v0, 1); v0 += __shfl_xor(v0, 2); v0 += __shfl_xor(v0, 4);
            v0 += __shfl_xor(v0, 8); v0 += __shfl_xor(v0, 16);
            v1 += __shfl_xor(v1, 1); v1 += __shfl_xor(v1, 2); v1 += __shfl_xor(v1, 4);
            v1 += __shfl_xor(v1, 8); v1 += __shfl_xor(v1, 16);
            if (lrow == 0){
                int row = (r & 3) + 8 * (r >> 2) + 4 * lh;   // 32x32 C/D mapping
                int ga = r0 + row, gb2 = r0 + 32 + row;
                if (ga  < 5000) logits[b * 5000 + ga]  = v0;
                if (gb2 < 5000) logits[b * 5000 + gb2] = v1;
            }
        }
    }
}

// ------- softmax over K per batch + scatter (zeroing done in stage 1) -------
__global__ void k_soft(const float* __restrict__ logits, const int* __restrict__ pairs,
                       float* __restrict__ out){
    int b = blockIdx.x, t = threadIdx.x;
    __shared__ float red[4];
    __shared__ float bmS, bsS;
    float* ob = out + (size_t)b * 10000;
    const float* lg = logits + b * 5000;
    float m = -1e30f;
    for (int j = t; j < 5000; j += 256) m = fmaxf(m, lg[j]);
    for (int s = 32; s >= 1; s >>= 1) m = fmaxf(m, __shfl_xor(m, s));
    if ((t & 63) == 0) red[t >> 6] = m;
    __syncthreads();
    if (t == 0) bmS = fmaxf(fmaxf(red[0], red[1]), fmaxf(red[2], red[3]));
    __syncthreads();
    float mm = bmS;
    float s = 0.f;
    for (int j = t; j < 5000; j += 256) s += __expf(lg[j] - mm);
    for (int k = 32; k >= 1; k >>= 1) s += __shfl_xor(s, k);
    if ((t & 63) == 0) red[t >> 6] = s;
    __syncthreads();
    if (t == 0) bsS = 1.0f / (red[0] + red[1] + red[2] + red[3]);
    __syncthreads();
    float inv = bsS;
    for (int j = t; j < 5000; j += 256){
        int pos = pairs[b * 5000 + j];
        ob[pos] = __expf(lg[j] - mm) * inv;
    }
}

extern "C" void kernel_launch(void* const* d_in, const int* in_sizes, int n_in,
                              void* d_out, int out_size, void* d_ws, size_t ws_size,
                              hipStream_t stream) {
    (void)in_sizes; (void)n_in; (void)out_size; (void)ws_size;
    const float* ef  = (const float*)d_in[0];
    const float* aW1 = (const float*)d_in[1];
    const float* ab1 = (const float*)d_in[2];
    const float* aW2 = (const float*)d_in[3];
    const float* ab2 = (const float*)d_in[4];
    const float* aW3 = (const float*)d_in[5];
    // d_in[6] = ab3: constant shift, cancels in softmax
    const float* cW1 = (const float*)d_in[7];
    const float* cb1 = (const float*)d_in[8];
    const float* cW2 = (const float*)d_in[9];
    const float* cb2 = (const float*)d_in[10];
    const float* cW3 = (const float*)d_in[11];
    const float* cb3 = (const float*)d_in[12];
    // d_in[13] = K, known = 5000
    float* out = (float*)d_out;
    char* ws = (char*)d_ws;
    int*   pairs  = (int*)(ws + 0);                         // 640,000 B
    float* logits = (float*)(ws + 640000);                  // 640,000 B
    unsigned short* P1 = (unsigned short*)(ws + 1411072);   // 6,553,600 B (bf16)
    unsigned short* P2 = (unsigned short*)(ws + 7964672);   // 6,553,600 B (bf16)
    unsigned char*  w2b = (unsigned char*)(ws + 14518272);  // 524,288 B (fp4 blocked)
    unsigned short* w1t = (unsigned short*)(ws + 15566848); // 1,048,576 B
    int*   qctr   = (int*)(ws + 16615424);                  // 128 B (queue counter)

    k_stage1<<<761,  256, 0, stream>>>(ef, aW1, aW2, cW1, cb1, cW2, cb2, cW3, cb3,
                                       pairs, w1t, w2b, out, qctr);
    k_p     <<<1024, 256, 0, stream>>>(ef, w1t, P1, aW1, ab1);
    k_main  <<<512,  256, 0, stream>>>(pairs, P1, P2, w2b, ab2, aW3, logits, qctr);
    k_soft  <<<32,   256, 0, stream>>>(logits, pairs, out);
}

// Round 13
// 322.274 us; speedup vs baseline: 1.2423x; 1.2423x over previous
//
#include <hip/hip_runtime.h>
#include <stdint.h>

#define AS1 __attribute__((address_space(1)))
#define AS3 __attribute__((address_space(3)))

typedef __bf16 bf16x8 __attribute__((ext_vector_type(8)));
typedef float  f32x4  __attribute__((ext_vector_type(4)));
typedef int    i32x4  __attribute__((ext_vector_type(4)));
typedef int    i32x8  __attribute__((ext_vector_type(8)));
typedef float  f32x16 __attribute__((ext_vector_type(16)));

// tanh(x) = 1 - 2/(exp(2x)+1) with fast v_rcp. |err| ~1e-7, exact at +/-inf.
__device__ __forceinline__ float tanh_fast(float x){
    float e = __expf(2.0f * x);
    return 1.0f - 2.0f * __builtin_amdgcn_rcpf(e + 1.0f);
}
// 4*tanh(x) (so fp4 e2m1 of result + MFMA scale 2^-2 reconstructs tanh)
__device__ __forceinline__ float tanh4_fast(float x){
    float e = __expf(2.0f * x);
    return fmaf(-8.0f, __builtin_amdgcn_rcpf(e + 1.0f), 4.0f);
}

__device__ __forceinline__ unsigned short f2bf(float f){
    unsigned int u = __float_as_uint(f);
    u = (u + 0x7fffu + ((u >> 16) & 1u)) >> 16;   // RNE
    return (unsigned short)u;
}

// pack 2 floats (range (-4,4)) as 2 e2m1 nibbles into byte SEL of `old`.
template<int SEL>
__device__ __forceinline__ unsigned int pk4(unsigned int old, float a, float b){
#if defined(__has_builtin) && __has_builtin(__builtin_amdgcn_cvt_scalef32_pk_fp4_f32)
    return __builtin_amdgcn_cvt_scalef32_pk_fp4_f32(old, a, b, 1.0f, SEL);
#else
    float fa = fabsf(a), fb = fabsf(b);
    unsigned int ma = fa < 0.25f ? 0u : fa < 0.75f ? 1u : fa < 1.25f ? 2u :
                      fa < 1.75f ? 3u : fa < 2.5f  ? 4u : fa < 3.5f  ? 5u :
                      fa < 5.0f  ? 6u : 7u;
    unsigned int mb = fb < 0.25f ? 0u : fb < 0.75f ? 1u : fb < 1.25f ? 2u :
                      fb < 1.75f ? 3u : fb < 2.5f  ? 4u : fb < 3.5f  ? 5u :
                      fb < 5.0f  ? 6u : 7u;
    ma |= (a < 0.0f ? 8u : 0u); mb |= (b < 0.0f ? 8u : 0u);
    return old | ((ma | (mb << 4)) << (8 * SEL));
#endif
}

// lower-half = a, upper-half undef (cbsz=4/blgp=4 -> HW reads only v[0:3])
__device__ __forceinline__ i32x8 lo4(i32x4 a){
    return __builtin_shufflevector(a, a, 0, 1, 2, 3, -1, -1, -1, -1);
}

// unpack 2 bf16 (one uint) -> 2 floats
#define B2F(u, lo, hi) { lo = __uint_as_float((u) << 16); hi = __uint_as_float((u) & 0xffff0000u); }

// ========== stage 1 (single launch): P-blocks | pairs | w2b(fp4) | value-head ==========
__global__ __launch_bounds__(256) void k_stage1(
    const float* __restrict__ ef,  const float* __restrict__ aW1, const float* __restrict__ ab1,
    const float* __restrict__ aW2,
    const float* __restrict__ cW1, const float* __restrict__ cb1,
    const float* __restrict__ cW2, const float* __restrict__ cb2,
    const float* __restrict__ cW3, const float* __restrict__ cb3,
    int* __restrict__ pairs, unsigned char* __restrict__ w2b,
    unsigned short* __restrict__ P, float* __restrict__ out, int* __restrict__ qctr)
{
    int blk = blockIdx.x;
    int t = threadIdx.x;
    __shared__ __align__(16) unsigned short an[112 * 264];   // 59136 B (P-blocks)
    __shared__ float gsh[256], gpart[4][64];
    __shared__ int s_base, s_woff[4], s_wc[4];
    __shared__ float gs[256], h1[512], h2[512], wred[4];

    if (blk == 1024 && t == 0) qctr[0] = 0;   // queue counter for k_main (re-init each launch)

    if (blk < 1024){
        // ---- P{1,2}[b][node][c] = nodes_b @ bf16(aW1 slice) (+g1+ab1 for s=0), bf16 out ----
        int cb = blk & 15, s = (blk >> 4) & 1, b = blk >> 5;
        for (int e = t; e < 25600; e += 256){            // stage nodes as bf16
            int row = e >> 8, col = e & 255;
            an[row * 264 + col] = f2bf(ef[(size_t)b * 35956 + (size_t)(1 + row) * 356 + col]);
        }
        for (int e = t; e < 3168; e += 256) an[26400 + e] = 0;  // zero pad rows 100..111
        gsh[t] = ef[(size_t)b * 35956 + t];              // g vector (for s=0 g1 slice)
        __syncthreads();

        if (s == 0){                                     // inline g1 partial: 4 quarters x 64 cols
            int cl = t & 63, q = t >> 6;
            const float* a1p = aW1 + (size_t)(q * 64) * 1024 + cb * 64 + cl;
            float p = 0.f;
            for (int i = 0; i < 64; ++i) p += gsh[q * 64 + i] * a1p[(size_t)i * 1024];
            gpart[q][cl] = p;
        }
        __syncthreads();

        int w = t >> 6, lane = t & 63, quad = lane >> 4, n = lane & 15;
        int c = cb * 64 + w * 16 + n;
        bf16x8 bfr[8];
        const float* wp = aW1 + (size_t)(256 + s * 256 + quad * 8) * 1024 + c;
#pragma unroll
        for (int kt = 0; kt < 8; ++kt){
            unsigned int ww[4];
#pragma unroll
            for (int jj = 0; jj < 4; ++jj){
                unsigned short lo = f2bf(wp[(size_t)(kt * 32 + 2 * jj) * 1024]);
                unsigned short hi = f2bf(wp[(size_t)(kt * 32 + 2 * jj + 1) * 1024]);
                ww[jj] = (unsigned int)lo | ((unsigned int)hi << 16);
            }
            uint4 pk = make_uint4(ww[0], ww[1], ww[2], ww[3]);
            bfr[kt] = *(bf16x8*)&pk;
        }
        f32x4 acc[7];
#pragma unroll
        for (int m = 0; m < 7; ++m){ f32x4 z = {0.f, 0.f, 0.f, 0.f}; acc[m] = z; }
#pragma unroll
        for (int kt = 0; kt < 8; ++kt){
#pragma unroll
            for (int m = 0; m < 7; ++m){
                const bf16x8* ap = (const bf16x8*)(an + (m * 16 + n) * 264 + kt * 32 + quad * 8);
                acc[m] = __builtin_amdgcn_mfma_f32_16x16x32_bf16(*ap, bfr[kt], acc[m], 0, 0, 0);
            }
        }
        int cw = w * 16 + n;
        float addv = (s == 0)
            ? (gpart[0][cw] + gpart[1][cw] + gpart[2][cw] + gpart[3][cw] + ab1[c]) : 0.0f;
        size_t base = (size_t)s * 3276800 + (size_t)b * 102400;
#pragma unroll
        for (int m = 0; m < 7; ++m){
            int r0 = m * 16 + quad * 4;
#pragma unroll
            for (int r = 0; r < 4; ++r){
                int row = r0 + r;
                if (row < 100) P[base + (size_t)row * 1024 + c] = f2bf(acc[m][r] + addv);
            }
        }
    } else if (blk < 1056){
        // ---- deterministic compaction of active mask positions ----
        int b = blk - 1024;
        if (t == 0) s_base = 0;
        __syncthreads();
        int lane = t & 63, w = t >> 6;
        for (int ch = 0; ch < 40; ++ch){
            int pos = ch * 256 + t;
            bool valid = false;
            if (pos < 10000){
                int r = pos / 100, c = pos - (pos / 100) * 100;
                valid = ef[(size_t)b * 35956 + (size_t)(1 + r) * 356 + 256 + c] != 0.0f;
            }
            unsigned long long bal = __ballot(valid);
            if (lane == 0) s_wc[w] = __popcll(bal);
            __syncthreads();
            if (t == 0){
                int r = s_base;
                for (int q = 0; q < 4; ++q){ s_woff[q] = r; r += s_wc[q]; }
                s_base = r;
            }
            __syncthreads();
            if (valid){
                int rank = __popcll(bal & ((1ull << lane) - 1ull));
                int o = s_woff[w] + rank;
                if (o < 5000) pairs[b * 5000 + o] = pos;
            }
            __syncthreads();
        }
    } else if (blk < 1184){
        // ---- aW2 -> fp4 e2m1 x 2^-7 (uniform MX scale 0x78), B-operand blocked ----
        int tid = (blk - 1056) * 256 + t;               // 32768 threads
        int lane = tid & 63, kt = (tid >> 6) & 15, ct = tid >> 10;
        int lh = lane >> 5, n = lane & 31;
        const float* src = aW2 + (size_t)(kt * 64 + lh * 32) * 1024 + ct * 32 + n;
        unsigned int d[4] = {0u, 0u, 0u, 0u};
#pragma unroll
        for (int j = 0; j < 32; ++j){
            float a = src[(size_t)j * 1024] * 128.0f;   // undo 2^-7 scale
            float f = fabsf(a);
            unsigned int m = f < 0.25f ? 0u : f < 0.75f ? 1u : f < 1.25f ? 2u :
                             f < 1.75f ? 3u : f < 2.5f  ? 4u : f < 3.5f  ? 5u :
                             f < 5.0f  ? 6u : 7u;
            unsigned int nib = m | (a < 0.0f ? 8u : 0u);
            d[j >> 3] |= nib << (4 * (j & 7));
        }
        *(uint4*)(w2b + (size_t)(ct * 16 + kt) * 1024 + lane * 16) =
            make_uint4(d[0], d[1], d[2], d[3]);
    } else {
        // ---- value head (tiny, fp32) ----
        int b = blk - 1184;
        gs[t] = ef[(size_t)b * 35956 + t];
        __syncthreads();
        for (int o = t; o < 512; o += 256){
            float a = cb1[o];
            for (int i = 0; i < 256; ++i) a += gs[i] * cW1[(size_t)i * 512 + o];
            h1[o] = tanh_fast(a);
        }
        __syncthreads();
        for (int o = t; o < 512; o += 256){
            float a = cb2[o];
            for (int i = 0; i < 512; ++i) a += h1[i] * cW2[(size_t)i * 512 + o];
            h2[o] = tanh_fast(a);
        }
        __syncthreads();
        float p = h2[t] * cW3[t] + h2[t + 256] * cW3[t + 256];
        for (int m = 32; m >= 1; m >>= 1) p += __shfl_xor(p, m);
        if ((t & 63) == 0) wred[t >> 6] = p;
        __syncthreads();
        if (t == 0) out[320000 + b] = wred[0] + wred[1] + wred[2] + wred[3] + cb3[0];
    }
}

// ---------------- fused layer1-gather + fp4xfp4 MX layer2 GEMM + layer3 dot ----------------
// R11 structure (LDS dbuf staging, block queue) + undef-upper MFMA operands (no
// duplication movs) + aW3/ab2 direct from L2 (LDS 32.8KB) -> 4 blocks/CU, 16 waves.
__global__ __launch_bounds__(256, 4) void k_main(
    const int* __restrict__ pairs,
    const unsigned short* __restrict__ P1, const unsigned short* __restrict__ P2,
    const unsigned char* __restrict__ w2b, const float* __restrict__ ab2,
    const float* __restrict__ aW3, float* __restrict__ logits, int* __restrict__ qctr)
{
    __shared__ __align__(16) unsigned char wbuf[2][16384];
    __shared__ int s_tile;
    int t = threadIdx.x, w = t >> 6, lane = t & 63;
    int lrow = lane & 31, lh = lane >> 5;
    int soff = w * 4096 + lane * 16;       // wave w stages 4KB of each 16KB stage

    for (;;){
        if (t == 0) s_tile = atomicAdd(qctr, 1);
        __syncthreads();                   // also isolates prev tile's LDS use
        int tt = s_tile;
        if (tt >= 1280) break;
        int b = tt / 40, tile = tt - b * 40;

        // prefetch ct=0 into wbuf[0]; phase 1 covers its latency
        {
            const unsigned char* s = w2b + soff;
            unsigned char* d = &wbuf[0][0] + soff;
#pragma unroll
            for (int i = 0; i < 4; ++i)
                __builtin_amdgcn_global_load_lds((AS1 void*)(s + i * 1024),
                                                 (AS3 void*)(d + i * 1024), 16, 0, 0);
        }

        int grow = tile * 128 + w * 32 + lrow;
        int pidx = pairs[b * 5000 + (grow < 5000 ? grow : 4999)];
        int i1 = pidx / 100, i2 = pidx - i1 * 100;
        const uint4* pa = (const uint4*)(P1 + (((size_t)(b * 100 + i1)) << 10)) + lh * 4;
        const uint4* pb = (const uint4*)(P2 + (((size_t)(b * 100 + i2)) << 10)) + lh * 4;

        // phase 1: af4[kt] nibble p (p=0..31) = e2m1(4*tanh(P1+P2)) at k = kt*64 + lh*32 + p
        i32x4 af4[16];
#pragma unroll
        for (int kt = 0; kt < 16; ++kt){
            uint4 qa[4], qb[4];
#pragma unroll
            for (int j = 0; j < 4; ++j){ qa[j] = pa[kt * 8 + j]; qb[j] = pb[kt * 8 + j]; }
            unsigned int d[4];
#pragma unroll
            for (int j = 0; j < 4; ++j){
                float a0, a1, b0, b1;
                unsigned int dd = 0;
                B2F(qa[j].x, a0, a1); B2F(qb[j].x, b0, b1);
                dd = pk4<0>(dd, tanh4_fast(a0 + b0), tanh4_fast(a1 + b1));
                B2F(qa[j].y, a0, a1); B2F(qb[j].y, b0, b1);
                dd = pk4<1>(dd, tanh4_fast(a0 + b0), tanh4_fast(a1 + b1));
                B2F(qa[j].z, a0, a1); B2F(qb[j].z, b0, b1);
                dd = pk4<2>(dd, tanh4_fast(a0 + b0), tanh4_fast(a1 + b1));
                B2F(qa[j].w, a0, a1); B2F(qb[j].w, b0, b1);
                dd = pk4<3>(dd, tanh4_fast(a0 + b0), tanh4_fast(a1 + b1));
                d[j] = dd;
            }
            i32x4 f = {(int)d[0], (int)d[1], (int)d[2], (int)d[3]};
            af4[kt] = f;
        }

        float prt[16];
#pragma unroll
        for (int r = 0; r < 16; ++r) prt[r] = 0.f;
        f32x16 acc0, acc1;

        // 32 col-tiles; stage ct (32 cols x 1024 k, fp4 = 16KB) in wbuf[ct&1]
        for (int ct = 0; ct < 32; ++ct){
            __syncthreads();                          // wbuf[ct&1] staged for all waves
            if (ct < 31){
                const unsigned char* sp = w2b + (size_t)(ct + 1) * 16384 + soff;
                unsigned char* d = &wbuf[(ct + 1) & 1][0] + soff;
#pragma unroll
                for (int i = 0; i < 4; ++i)
                    __builtin_amdgcn_global_load_lds((AS1 void*)(sp + i * 1024),
                                                     (AS3 void*)(d + i * 1024), 16, 0, 0);
            }
#pragma unroll
            for (int r = 0; r < 16; ++r){ acc0[r] = 0.f; acc1[r] = 0.f; }
            const unsigned char* bb = &wbuf[ct & 1][0] + lane * 16;
#pragma unroll
            for (int j = 0; j < 8; ++j){
                uint4 q0 = *(const uint4*)(bb + (2 * j) * 1024);
                uint4 q1 = *(const uint4*)(bb + (2 * j + 1) * 1024);
                i32x4 b0 = {(int)q0.x, (int)q0.y, (int)q0.z, (int)q0.w};
                i32x4 b1 = {(int)q1.x, (int)q1.y, (int)q1.z, (int)q1.w};
                // cbsz=4: A fp4 (scale 2^-2 = 0x7D); blgp=4: B fp4 (scale 2^-7 = 0x78)
                acc0 = __builtin_amdgcn_mfma_scale_f32_32x32x64_f8f6f4(
                           lo4(af4[2 * j]),     lo4(b0), acc0, 4, 4, 0, 0x7D7D7D7D, 0, 0x78787878);
                acc1 = __builtin_amdgcn_mfma_scale_f32_32x32x64_f8f6f4(
                           lo4(af4[2 * j + 1]), lo4(b1), acc1, 4, 4, 0, 0x7D7D7D7D, 0, 0x78787878);
            }
            int c = ct * 32 + lrow;
            float w3 = aW3[c], bias = ab2[c];
#pragma unroll
            for (int r = 0; r < 16; ++r)
                prt[r] += tanh_fast(acc0[r] + acc1[r] + bias) * w3;
        }

        // reduce each reg's partial over the 32 cols (lanes within each half-wave)
#pragma unroll
        for (int r = 0; r < 16; ++r){
            float v = prt[r];
            v += __shfl_xor(v, 1); v += __shfl_xor(v, 2); v += __shfl_xor(v, 4);
            v += __shfl_xor(v, 8); v += __shfl_xor(v, 16);
            if (lrow == 0){
                int row = (r & 3) + 8 * (r >> 2) + 4 * lh;   // 32x32 C/D mapping
                int g = tile * 128 + w * 32 + row;
                if (g < 5000) logits[b * 5000 + g] = v;
            }
        }
    }
}

// ------- zero filled region + softmax over K per batch + scatter -------
__global__ void k_soft(const float* __restrict__ logits, const int* __restrict__ pairs,
                       float* __restrict__ out){
    int b = blockIdx.x, t = threadIdx.x;
    __shared__ float red[4];
    __shared__ float bmS, bsS;
    float* ob = out + (size_t)b * 10000;
    for (int j = t; j < 10000; j += 256) ob[j] = 0.0f;
    const float* lg = logits + b * 5000;
    float m = -1e30f;
    for (int j = t; j < 5000; j += 256) m = fmaxf(m, lg[j]);
    for (int s = 32; s >= 1; s >>= 1) m = fmaxf(m, __shfl_xor(m, s));
    if ((t & 63) == 0) red[t >> 6] = m;
    __syncthreads();
    if (t == 0) bmS = fmaxf(fmaxf(red[0], red[1]), fmaxf(red[2], red[3]));
    __syncthreads();
    float mm = bmS;
    float s = 0.f;
    for (int j = t; j < 5000; j += 256) s += __expf(lg[j] - mm);
    for (int k = 32; k >= 1; k >>= 1) s += __shfl_xor(s, k);
    if ((t & 63) == 0) red[t >> 6] = s;
    __syncthreads();
    if (t == 0) bsS = 1.0f / (red[0] + red[1] + red[2] + red[3]);
    __syncthreads();
    float inv = bsS;
    for (int j = t; j < 5000; j += 256){
        int pos = pairs[b * 5000 + j];
        ob[pos] = __expf(lg[j] - mm) * inv;
    }
}

extern "C" void kernel_launch(void* const* d_in, const int* in_sizes, int n_in,
                              void* d_out, int out_size, void* d_ws, size_t ws_size,
                              hipStream_t stream) {
    (void)in_sizes; (void)n_in; (void)out_size; (void)ws_size;
    const float* ef  = (const float*)d_in[0];
    const float* aW1 = (const float*)d_in[1];
    const float* ab1 = (const float*)d_in[2];
    const float* aW2 = (const float*)d_in[3];
    const float* ab2 = (const float*)d_in[4];
    const float* aW3 = (const float*)d_in[5];
    // d_in[6] = ab3: constant shift, cancels in softmax
    const float* cW1 = (const float*)d_in[7];
    const float* cb1 = (const float*)d_in[8];
    const float* cW2 = (const float*)d_in[9];
    const float* cb2 = (const float*)d_in[10];
    const float* cW3 = (const float*)d_in[11];
    const float* cb3 = (const float*)d_in[12];
    // d_in[13] = K, known = 5000
    float* out = (float*)d_out;
    char* ws = (char*)d_ws;
    int*   pairs  = (int*)(ws + 0);                         // 640,000 B
    float* logits = (float*)(ws + 640000);                  // 640,000 B
    unsigned short* P1 = (unsigned short*)(ws + 1411072);   // 6,553,600 B (bf16)
    unsigned short* P2 = (unsigned short*)(ws + 7964672);   // 6,553,600 B (bf16)
    unsigned char*  w2b = (unsigned char*)(ws + 14518272);  // 524,288 B (fp4 blocked)
    int*   qctr   = (int*)(ws + 16615424);                  // 128 B (queue counter)

    k_stage1<<<1216, 256, 0, stream>>>(ef, aW1, ab1, aW2, cW1, cb1, cW2, cb2, cW3, cb3,
                                       pairs, w2b, P1, out, qctr);
    k_main  <<<1024, 256, 0, stream>>>(pairs, P1, P2, w2b, ab2, aW3, logits, qctr);
    k_soft  <<<32,   256, 0, stream>>>(logits, pairs, out);
}

// Round 14
// 307.671 us; speedup vs baseline: 1.3012x; 1.0475x over previous
//
#include <hip/hip_runtime.h>
#include <stdint.h>

#define AS1 __attribute__((address_space(1)))
#define AS3 __attribute__((address_space(3)))

typedef __bf16 bf16x8 __attribute__((ext_vector_type(8)));
typedef float  f32x4  __attribute__((ext_vector_type(4)));
typedef int    i32x4  __attribute__((ext_vector_type(4)));
typedef int    i32x8  __attribute__((ext_vector_type(8)));
typedef float  f32x16 __attribute__((ext_vector_type(16)));

// tanh(x) = 1 - 2/(exp(2x)+1) with fast v_rcp. |err| ~1e-7, exact at +/-inf.
__device__ __forceinline__ float tanh_fast(float x){
    float e = __expf(2.0f * x);
    return 1.0f - 2.0f * __builtin_amdgcn_rcpf(e + 1.0f);
}
// 4*tanh(x) (so fp4 e2m1 of result + MFMA scale 2^-2 reconstructs tanh)
__device__ __forceinline__ float tanh4_fast(float x){
    float e = __expf(2.0f * x);
    return fmaf(-8.0f, __builtin_amdgcn_rcpf(e + 1.0f), 4.0f);
}

__device__ __forceinline__ unsigned short f2bf(float f){
    unsigned int u = __float_as_uint(f);
    u = (u + 0x7fffu + ((u >> 16) & 1u)) >> 16;   // RNE
    return (unsigned short)u;
}

// pack 2 floats (range (-4,4)) as 2 e2m1 nibbles into byte SEL of `old`.
template<int SEL>
__device__ __forceinline__ unsigned int pk4(unsigned int old, float a, float b){
#if defined(__has_builtin) && __has_builtin(__builtin_amdgcn_cvt_scalef32_pk_fp4_f32)
    return __builtin_amdgcn_cvt_scalef32_pk_fp4_f32(old, a, b, 1.0f, SEL);
#else
    float fa = fabsf(a), fb = fabsf(b);
    unsigned int ma = fa < 0.25f ? 0u : fa < 0.75f ? 1u : fa < 1.25f ? 2u :
                      fa < 1.75f ? 3u : fa < 2.5f  ? 4u : fa < 3.5f  ? 5u :
                      fa < 5.0f  ? 6u : 7u;
    unsigned int mb = fb < 0.25f ? 0u : fb < 0.75f ? 1u : fb < 1.25f ? 2u :
                      fb < 1.75f ? 3u : fb < 2.5f  ? 4u : fb < 3.5f  ? 5u :
                      fb < 5.0f  ? 6u : 7u;
    ma |= (a < 0.0f ? 8u : 0u); mb |= (b < 0.0f ? 8u : 0u);
    return old | ((ma | (mb << 4)) << (8 * SEL));
#endif
}

// lower-half = a, upper-half undef (cbsz=4/blgp=4 -> HW reads only v[0:3])
__device__ __forceinline__ i32x8 lo4(i32x4 a){
    return __builtin_shufflevector(a, a, 0, 1, 2, 3, -1, -1, -1, -1);
}

// unpack 2 bf16 (one uint) -> 2 floats
#define B2F(u, lo, hi) { lo = __uint_as_float((u) << 16); hi = __uint_as_float((u) & 0xffff0000u); }

// ========== stage 1 (single launch): fused-s P-blocks | pairs | w2b(fp4) | value-head ==========
__global__ __launch_bounds__(256) void k_stage1(
    const float* __restrict__ ef,  const float* __restrict__ aW1, const float* __restrict__ ab1,
    const float* __restrict__ aW2,
    const float* __restrict__ cW1, const float* __restrict__ cb1,
    const float* __restrict__ cW2, const float* __restrict__ cb2,
    const float* __restrict__ cW3, const float* __restrict__ cb3,
    int* __restrict__ pairs, unsigned char* __restrict__ w2b,
    unsigned short* __restrict__ P, float* __restrict__ out, int* __restrict__ qctr)
{
    int blk = blockIdx.x;
    int t = threadIdx.x;
    __shared__ __align__(16) unsigned short an[112 * 264];   // 59136 B (P-blocks)
    __shared__ float gsh[256], gpart[4][64];
    __shared__ int s_base, s_woff[4], s_wc[4];
    __shared__ float gs[256], h1[512], h2[512], wred[4];

    if (blk == 512 && t == 0) qctr[0] = 0;   // queue counter for k_main (re-init each launch)

    if (blk < 512){
        // ---- P1/P2[b][node][c] = nodes_b @ bf16(aW1 slices), staged ONCE per (b,cb) ----
        int cb = blk & 15, b = blk >> 4;
        for (int e = t; e < 25600; e += 256){            // stage nodes as bf16
            int row = e >> 8, col = e & 255;
            an[row * 264 + col] = f2bf(ef[(size_t)b * 35956 + (size_t)(1 + row) * 356 + col]);
        }
        for (int e = t; e < 3168; e += 256) an[26400 + e] = 0;  // zero pad rows 100..111
        gsh[t] = ef[(size_t)b * 35956 + t];              // g vector (for g1 slice)
        __syncthreads();

        {                                                // inline g1 partial: 4 quarters x 64 cols
            int cl = t & 63, q = t >> 6;
            const float* a1p = aW1 + (size_t)(q * 64) * 1024 + cb * 64 + cl;
            float p = 0.f;
            for (int i = 0; i < 64; ++i) p += gsh[q * 64 + i] * a1p[(size_t)i * 1024];
            gpart[q][cl] = p;
        }
        __syncthreads();

        int w = t >> 6, lane = t & 63, quad = lane >> 4, n = lane & 15;
        int c = cb * 64 + w * 16 + n;
        bf16x8 bfr0[8], bfr1[8];                         // s=0 and s=1 weight slices
        const float* wp0 = aW1 + (size_t)(256 + quad * 8) * 1024 + c;
        const float* wp1 = aW1 + (size_t)(512 + quad * 8) * 1024 + c;
#pragma unroll
        for (int kt = 0; kt < 8; ++kt){
            unsigned int w0[4], w1[4];
#pragma unroll
            for (int jj = 0; jj < 4; ++jj){
                size_t off0 = (size_t)(kt * 32 + 2 * jj) * 1024;
                size_t off1 = off0 + 1024;
                w0[jj] = (unsigned int)f2bf(wp0[off0]) | ((unsigned int)f2bf(wp0[off1]) << 16);
                w1[jj] = (unsigned int)f2bf(wp1[off0]) | ((unsigned int)f2bf(wp1[off1]) << 16);
            }
            uint4 p0 = make_uint4(w0[0], w0[1], w0[2], w0[3]);
            uint4 p1 = make_uint4(w1[0], w1[1], w1[2], w1[3]);
            bfr0[kt] = *(bf16x8*)&p0;
            bfr1[kt] = *(bf16x8*)&p1;
        }
        f32x4 acc0[7], acc1[7];
#pragma unroll
        for (int m = 0; m < 7; ++m){ f32x4 z = {0.f, 0.f, 0.f, 0.f}; acc0[m] = z; acc1[m] = z; }
#pragma unroll
        for (int kt = 0; kt < 8; ++kt){
#pragma unroll
            for (int m = 0; m < 7; ++m){
                const bf16x8* ap = (const bf16x8*)(an + (m * 16 + n) * 264 + kt * 32 + quad * 8);
                bf16x8 av = *ap;                         // one LDS read feeds BOTH MFMAs
                acc0[m] = __builtin_amdgcn_mfma_f32_16x16x32_bf16(av, bfr0[kt], acc0[m], 0, 0, 0);
                acc1[m] = __builtin_amdgcn_mfma_f32_16x16x32_bf16(av, bfr1[kt], acc1[m], 0, 0, 0);
            }
        }
        int cw = w * 16 + n;
        float addv = gpart[0][cw] + gpart[1][cw] + gpart[2][cw] + gpart[3][cw] + ab1[c];
        size_t base = (size_t)b * 102400;
#pragma unroll
        for (int m = 0; m < 7; ++m){
            int r0 = m * 16 + quad * 4;
#pragma unroll
            for (int r = 0; r < 4; ++r){
                int row = r0 + r;
                if (row < 100){
                    P[base + (size_t)row * 1024 + c]           = f2bf(acc0[m][r] + addv);
                    P[3276800 + base + (size_t)row * 1024 + c] = f2bf(acc1[m][r]);
                }
            }
        }
    } else if (blk < 544){
        // ---- deterministic compaction of active mask positions ----
        int b = blk - 512;
        if (t == 0) s_base = 0;
        __syncthreads();
        int lane = t & 63, w = t >> 6;
        for (int ch = 0; ch < 40; ++ch){
            int pos = ch * 256 + t;
            bool valid = false;
            if (pos < 10000){
                int r = pos / 100, c = pos - (pos / 100) * 100;
                valid = ef[(size_t)b * 35956 + (size_t)(1 + r) * 356 + 256 + c] != 0.0f;
            }
            unsigned long long bal = __ballot(valid);
            if (lane == 0) s_wc[w] = __popcll(bal);
            __syncthreads();
            if (t == 0){
                int r = s_base;
                for (int q = 0; q < 4; ++q){ s_woff[q] = r; r += s_wc[q]; }
                s_base = r;
            }
            __syncthreads();
            if (valid){
                int rank = __popcll(bal & ((1ull << lane) - 1ull));
                int o = s_woff[w] + rank;
                if (o < 5000) pairs[b * 5000 + o] = pos;
            }
            __syncthreads();
        }
    } else if (blk < 672){
        // ---- aW2 -> fp4 e2m1 x 2^-7 (uniform MX scale 0x78), B-operand blocked ----
        int tid = (blk - 544) * 256 + t;                // 32768 threads
        int lane = tid & 63, kt = (tid >> 6) & 15, ct = tid >> 10;
        int lh = lane >> 5, n = lane & 31;
        const float* src = aW2 + (size_t)(kt * 64 + lh * 32) * 1024 + ct * 32 + n;
        unsigned int d[4] = {0u, 0u, 0u, 0u};
#pragma unroll
        for (int j = 0; j < 32; ++j){
            float a = src[(size_t)j * 1024] * 128.0f;   // undo 2^-7 scale
            float f = fabsf(a);
            unsigned int m = f < 0.25f ? 0u : f < 0.75f ? 1u : f < 1.25f ? 2u :
                             f < 1.75f ? 3u : f < 2.5f  ? 4u : f < 3.5f  ? 5u :
                             f < 5.0f  ? 6u : 7u;
            unsigned int nib = m | (a < 0.0f ? 8u : 0u);
            d[j >> 3] |= nib << (4 * (j & 7));
        }
        *(uint4*)(w2b + (size_t)(ct * 16 + kt) * 1024 + lane * 16) =
            make_uint4(d[0], d[1], d[2], d[3]);
    } else {
        // ---- value head (tiny, fp32) ----
        int b = blk - 672;
        gs[t] = ef[(size_t)b * 35956 + t];
        __syncthreads();
        for (int o = t; o < 512; o += 256){
            float a = cb1[o];
            for (int i = 0; i < 256; ++i) a += gs[i] * cW1[(size_t)i * 512 + o];
            h1[o] = tanh_fast(a);
        }
        __syncthreads();
        for (int o = t; o < 512; o += 256){
            float a = cb2[o];
            for (int i = 0; i < 512; ++i) a += h1[i] * cW2[(size_t)i * 512 + o];
            h2[o] = tanh_fast(a);
        }
        __syncthreads();
        float p = h2[t] * cW3[t] + h2[t + 256] * cW3[t + 256];
        for (int m = 32; m >= 1; m >>= 1) p += __shfl_xor(p, m);
        if ((t & 63) == 0) wred[t >> 6] = p;
        __syncthreads();
        if (t == 0) out[320000 + b] = wred[0] + wred[1] + wred[2] + wred[3] + cb3[0];
    }
}

// ---------------- fused layer1-gather + fp4xfp4 MX layer2 GEMM + layer3 dot ----------------
// R11 staging structure; SINGLE acc chain per ct (saves 16 regs vs two chains) so the
// (256,4) cap (128 unified regs) holds without spill: af4(64)+acc(16)+prt(16)+temps.
__global__ __launch_bounds__(256, 4) void k_main(
    const int* __restrict__ pairs,
    const unsigned short* __restrict__ P1, const unsigned short* __restrict__ P2,
    const unsigned char* __restrict__ w2b, const float* __restrict__ ab2,
    const float* __restrict__ aW3, float* __restrict__ logits, int* __restrict__ qctr)
{
    __shared__ __align__(16) unsigned char wbuf[2][16384];
    __shared__ int s_tile;
    int t = threadIdx.x, w = t >> 6, lane = t & 63;
    int lrow = lane & 31, lh = lane >> 5;
    int soff = w * 4096 + lane * 16;       // wave w stages 4KB of each 16KB stage

    for (;;){
        if (t == 0) s_tile = atomicAdd(qctr, 1);
        __syncthreads();                   // also isolates prev tile's LDS use
        int tt = s_tile;
        if (tt >= 1280) break;
        int b = tt / 40, tile = tt - b * 40;

        // prefetch ct=0 into wbuf[0]; phase 1 covers its latency
        {
            const unsigned char* s = w2b + soff;
            unsigned char* d = &wbuf[0][0] + soff;
#pragma unroll
            for (int i = 0; i < 4; ++i)
                __builtin_amdgcn_global_load_lds((AS1 void*)(s + i * 1024),
                                                 (AS3 void*)(d + i * 1024), 16, 0, 0);
        }

        int grow = tile * 128 + w * 32 + lrow;
        int pidx = pairs[b * 5000 + (grow < 5000 ? grow : 4999)];
        int i1 = pidx / 100, i2 = pidx - i1 * 100;
        const uint4* pa = (const uint4*)(P1 + (((size_t)(b * 100 + i1)) << 10)) + lh * 4;
        const uint4* pb = (const uint4*)(P2 + (((size_t)(b * 100 + i2)) << 10)) + lh * 4;

        // phase 1: af4[kt] nibble p (p=0..31) = e2m1(4*tanh(P1+P2)) at k = kt*64 + lh*32 + p
        i32x4 af4[16];
#pragma unroll
        for (int kt = 0; kt < 16; ++kt){
            uint4 qa[4], qb[4];
#pragma unroll
            for (int j = 0; j < 4; ++j){ qa[j] = pa[kt * 8 + j]; qb[j] = pb[kt * 8 + j]; }
            unsigned int d[4];
#pragma unroll
            for (int j = 0; j < 4; ++j){
                float a0, a1, b0, b1;
                unsigned int dd = 0;
                B2F(qa[j].x, a0, a1); B2F(qb[j].x, b0, b1);
                dd = pk4<0>(dd, tanh4_fast(a0 + b0), tanh4_fast(a1 + b1));
                B2F(qa[j].y, a0, a1); B2F(qb[j].y, b0, b1);
                dd = pk4<1>(dd, tanh4_fast(a0 + b0), tanh4_fast(a1 + b1));
                B2F(qa[j].z, a0, a1); B2F(qb[j].z, b0, b1);
                dd = pk4<2>(dd, tanh4_fast(a0 + b0), tanh4_fast(a1 + b1));
                B2F(qa[j].w, a0, a1); B2F(qb[j].w, b0, b1);
                dd = pk4<3>(dd, tanh4_fast(a0 + b0), tanh4_fast(a1 + b1));
                d[j] = dd;
            }
            i32x4 f = {(int)d[0], (int)d[1], (int)d[2], (int)d[3]};
            af4[kt] = f;
        }

        float prt[16];
#pragma unroll
        for (int r = 0; r < 16; ++r) prt[r] = 0.f;
        f32x16 acc;

        // 32 col-tiles; stage ct (32 cols x 1024 k, fp4 = 16KB) in wbuf[ct&1]
        for (int ct = 0; ct < 32; ++ct){
            __syncthreads();                          // wbuf[ct&1] staged for all waves
            if (ct < 31){
                const unsigned char* sp = w2b + (size_t)(ct + 1) * 16384 + soff;
                unsigned char* d = &wbuf[(ct + 1) & 1][0] + soff;
#pragma unroll
                for (int i = 0; i < 4; ++i)
                    __builtin_amdgcn_global_load_lds((AS1 void*)(sp + i * 1024),
                                                     (AS3 void*)(d + i * 1024), 16, 0, 0);
            }
#pragma unroll
            for (int r = 0; r < 16; ++r) acc[r] = 0.f;
            const unsigned char* bb = &wbuf[ct & 1][0] + lane * 16;
#pragma unroll
            for (int kt = 0; kt < 16; ++kt){
                uint4 q = *(const uint4*)(bb + kt * 1024);
                i32x4 bq = {(int)q.x, (int)q.y, (int)q.z, (int)q.w};
                // cbsz=4: A fp4 (scale 2^-2 = 0x7D); blgp=4: B fp4 (scale 2^-7 = 0x78)
                acc = __builtin_amdgcn_mfma_scale_f32_32x32x64_f8f6f4(
                          lo4(af4[kt]), lo4(bq), acc, 4, 4, 0, 0x7D7D7D7D, 0, 0x78787878);
            }
            int c = ct * 32 + lrow;
            float w3 = aW3[c], bias = ab2[c];
#pragma unroll
            for (int r = 0; r < 16; ++r)
                prt[r] += tanh_fast(acc[r] + bias) * w3;
        }

        // reduce each reg's partial over the 32 cols (lanes within each half-wave)
#pragma unroll
        for (int r = 0; r < 16; ++r){
            float v = prt[r];
            v += __shfl_xor(v, 1); v += __shfl_xor(v, 2); v += __shfl_xor(v, 4);
            v += __shfl_xor(v, 8); v += __shfl_xor(v, 16);
            if (lrow == 0){
                int row = (r & 3) + 8 * (r >> 2) + 4 * lh;   // 32x32 C/D mapping
                int g = tile * 128 + w * 32 + row;
                if (g < 5000) logits[b * 5000 + g] = v;
            }
        }
    }
}

// ------- zero filled region + softmax over K per batch + scatter -------
__global__ void k_soft(const float* __restrict__ logits, const int* __restrict__ pairs,
                       float* __restrict__ out){
    int b = blockIdx.x, t = threadIdx.x;
    __shared__ float red[4];
    __shared__ float bmS, bsS;
    float* ob = out + (size_t)b * 10000;
    for (int j = t; j < 10000; j += 256) ob[j] = 0.0f;
    const float* lg = logits + b * 5000;
    float m = -1e30f;
    for (int j = t; j < 5000; j += 256) m = fmaxf(m, lg[j]);
    for (int s = 32; s >= 1; s >>= 1) m = fmaxf(m, __shfl_xor(m, s));
    if ((t & 63) == 0) red[t >> 6] = m;
    __syncthreads();
    if (t == 0) bmS = fmaxf(fmaxf(red[0], red[1]), fmaxf(red[2], red[3]));
    __syncthreads();
    float mm = bmS;
    float s = 0.f;
    for (int j = t; j < 5000; j += 256) s += __expf(lg[j] - mm);
    for (int k = 32; k >= 1; k >>= 1) s += __shfl_xor(s, k);
    if ((t & 63) == 0) red[t >> 6] = s;
    __syncthreads();
    if (t == 0) bsS = 1.0f / (red[0] + red[1] + red[2] + red[3]);
    __syncthreads();
    float inv = bsS;
    for (int j = t; j < 5000; j += 256){
        int pos = pairs[b * 5000 + j];
        ob[pos] = __expf(lg[j] - mm) * inv;
    }
}

extern "C" void kernel_launch(void* const* d_in, const int* in_sizes, int n_in,
                              void* d_out, int out_size, void* d_ws, size_t ws_size,
                              hipStream_t stream) {
    (void)in_sizes; (void)n_in; (void)out_size; (void)ws_size;
    const float* ef  = (const float*)d_in[0];
    const float* aW1 = (const float*)d_in[1];
    const float* ab1 = (const float*)d_in[2];
    const float* aW2 = (const float*)d_in[3];
    const float* ab2 = (const float*)d_in[4];
    const float* aW3 = (const float*)d_in[5];
    // d_in[6] = ab3: constant shift, cancels in softmax
    const float* cW1 = (const float*)d_in[7];
    const float* cb1 = (const float*)d_in[8];
    const float* cW2 = (const float*)d_in[9];
    const float* cb2 = (const float*)d_in[10];
    const float* cW3 = (const float*)d_in[11];
    const float* cb3 = (const float*)d_in[12];
    // d_in[13] = K, known = 5000
    float* out = (float*)d_out;
    char* ws = (char*)d_ws;
    int*   pairs  = (int*)(ws + 0);                         // 640,000 B
    float* logits = (float*)(ws + 640000);                  // 640,000 B
    unsigned short* P1 = (unsigned short*)(ws + 1411072);   // 6,553,600 B (bf16)
    unsigned short* P2 = (unsigned short*)(ws + 7964672);   // 6,553,600 B (bf16)
    unsigned char*  w2b = (unsigned char*)(ws + 14518272);  // 524,288 B (fp4 blocked)
    int*   qctr   = (int*)(ws + 16615424);                  // 128 B (queue counter)

    k_stage1<<<704,  256, 0, stream>>>(ef, aW1, ab1, aW2, cW1, cb1, cW2, cb2, cW3, cb3,
                                       pairs, w2b, P1, out, qctr);
    k_main  <<<1024, 256, 0, stream>>>(pairs, P1, P2, w2b, ab2, aW3, logits, qctr);
    k_soft  <<<32,   256, 0, stream>>>(logits, pairs, out);
}